// Round 14
// baseline (88.994 us; speedup 1.0000x reference)
//
#include <hip/hip_runtime.h>
#include <cstdint>
#include <cmath>

#define BB 1024
#define CC 256
#define SS 64
#define DD 128
#define TOPKN 8
#define EPSF 1e-8f

typedef __attribute__((ext_vector_type(8))) short short8;
typedef __attribute__((ext_vector_type(16))) float f32x16;

static __device__ __forceinline__ unsigned short f2bf(float x) {
    uint32_t u = __float_as_uint(x);
    uint32_t r = (u + 0x7FFFu + ((u >> 16) & 1u)) >> 16;   // RNE
    return (unsigned short)r;
}
static __device__ __forceinline__ float bf2f(unsigned short h) {
    return __uint_as_float(((uint32_t)h) << 16);
}

// u32 compare-exchange, descending. Packed key = (fmono(key)&~63)|(63-s):
// 2^-18-granular key + index tiebreak (lower s wins). Half the register cost
// of u64 -> fits the 128-reg budget of 4 waves/SIMD (no spill; proven R13).
#define CEX32(a, b) { uint32_t _h = (a) > (b) ? (a) : (b); \
                      uint32_t _l = (a) > (b) ? (b) : (a); (a) = _h; (b) = _l; }

static __device__ __forceinline__ void sort8_32(uint32_t* v) {
    CEX32(v[0],v[1]); CEX32(v[2],v[3]); CEX32(v[4],v[5]); CEX32(v[6],v[7]);
    CEX32(v[0],v[2]); CEX32(v[1],v[3]); CEX32(v[4],v[6]); CEX32(v[5],v[7]);
    CEX32(v[1],v[2]); CEX32(v[5],v[6]);
    CEX32(v[0],v[4]); CEX32(v[1],v[5]); CEX32(v[2],v[6]); CEX32(v[3],v[7]);
    CEX32(v[2],v[4]); CEX32(v[3],v[5]);
    CEX32(v[1],v[2]); CEX32(v[3],v[4]); CEX32(v[5],v[6]);
}
// run := top-8 (sorted desc) of run ∪ cur; both sorted desc (bitonic merge).
static __device__ __forceinline__ void merge8_32(uint32_t* run, const uint32_t* cur) {
    uint32_t t[8];
    #pragma unroll
    for (int i = 0; i < 8; i++) t[i] = run[i] > cur[7-i] ? run[i] : cur[7-i];
    CEX32(t[0],t[4]); CEX32(t[1],t[5]); CEX32(t[2],t[6]); CEX32(t[3],t[7]);
    CEX32(t[0],t[2]); CEX32(t[1],t[3]); CEX32(t[4],t[6]); CEX32(t[5],t[7]);
    CEX32(t[0],t[1]); CEX32(t[2],t[3]); CEX32(t[4],t[5]); CEX32(t[6],t[7]);
    #pragma unroll
    for (int i = 0; i < 8; i++) run[i] = t[i];
}

// monotone map: float bits -> u32 preserving order
static __device__ __forceinline__ uint32_t fmono(float x) {
    uint32_t u = __float_as_uint(x);
    return u ^ (uint32_t)(((int32_t)u >> 31) | 0x80000000);
}
static __device__ __forceinline__ float funmono(uint32_t m) {
    uint32_t u = (m & 0x80000000u) ? (m ^ 0x80000000u) : ~m;
    return __uint_as_float(u);
}

// ---- kernel A: split emb (raw) and weight (row-normalized) into bf16 hi/lo
//      MFMA fragments + exact fp32 norms. (proven since R6) ----
__global__ __launch_bounds__(256) void split_kernel(const float* __restrict__ emb,
                                                    const float* __restrict__ weight,
                                                    unsigned short* __restrict__ ehi,
                                                    unsigned short* __restrict__ elo,
                                                    unsigned short* __restrict__ whi,
                                                    unsigned short* __restrict__ wlo,
                                                    float* __restrict__ nemb,
                                                    float* __restrict__ nw_g) {
    int gid = blockIdx.x * 256 + threadIdx.x;   // 16 threads per row
    int row = gid >> 4, kg = gid & 15;
    bool isEmb = row < BB;
    int r = isEmb ? row : row - BB;
    const float* src = isEmb ? emb : weight;
    const float4* sp = (const float4*)(src + (size_t)r * DD + kg * 8);
    float4 v0 = sp[0], v1 = sp[1];
    float x[8] = {v0.x, v0.y, v0.z, v0.w, v1.x, v1.y, v1.z, v1.w};
    float ss = 0.f;
    #pragma unroll
    for (int j = 0; j < 8; j++) ss += x[j] * x[j];
    #pragma unroll
    for (int off = 8; off; off >>= 1) ss += __shfl_xor(ss, off);

    float scale;
    if (isEmb) {
        if (kg == 0) nemb[r] = sqrtf(ss);
        scale = 1.0f;
    } else {
        if (kg == 0) nw_g[r] = sqrtf(ss);
        scale = 1.0f / sqrtf(fmaxf(ss, 1e-30f));
    }
    short8 h8, l8;
    #pragma unroll
    for (int j = 0; j < 8; j++) {
        float xs = x[j] * scale;
        unsigned short h = f2bf(xs);
        h8[j] = (short)h;
        l8[j] = (short)f2bf(xs - bf2f(h));
    }
    size_t o = ((size_t)(r >> 5) * 8 + (kg >> 1)) * 64 + (kg & 1) * 32 + (r & 31);
    if (isEmb) { ((short8*)ehi)[o] = h8; ((short8*)elo)[o] = l8; }
    else       { ((short8*)whi)[o] = h8; ((short8*)wlo)[o] = l8; }
}

// ---- kernel B (fused, transposed GEMM): D[s][b] = Wn[c] . emb^T.
//      R14: software-pipelined e-frag loads (depth-1 double buffer; t=0 issued
//      before the staging barrier) — hides ~200cyc L2 latency behind 12 MFMAs.
//      (256,4): peak live ~122 regs < 128 budget -> no spill; 4/CU, no tail. ----
__global__ __launch_bounds__(256, 4) void main_kernel(const unsigned short* __restrict__ ehi,
                                                      const unsigned short* __restrict__ elo,
                                                      const unsigned short* __restrict__ whi,
                                                      const unsigned short* __restrict__ wlo,
                                                      const float* __restrict__ nw_g,
                                                      const float* __restrict__ nemb,
                                                      float* __restrict__ out) {
    __shared__ __align__(16) float uni[8192];   // 32 KB: Ws, later Gs (16 KB)
    __shared__ float nwL[SS];
    short8* WsH = (short8*)uni;                 // [tile(2)][t(8)][lane(64)]
    short8* WsL = WsH + 1024;
    float* Gs = uni;                            // life 2: Gn 64x64

    int tid = threadIdx.x, lane = tid & 63, w = tid >> 6;
    int q = lane >> 5, col = lane & 31;
    int c = blockIdx.y, b0 = blockIdx.x * 256;

    // ---- life 1: stage W[c] fragments + nw[c] ----
    const short8* whg = (const short8*)whi + (size_t)c * 1024;
    const short8* wlg = (const short8*)wlo + (size_t)c * 1024;
    #pragma unroll
    for (int j = 0; j < 4; j++) {
        WsH[j * 256 + tid] = whg[j * 256 + tid];
        WsL[j * 256 + tid] = wlg[j * 256 + tid];
    }
    if (tid < SS) nwL[tid] = nw_g[c * SS + tid];

    // prefetch t=0 e-frags BEFORE the barrier (independent of LDS contents)
    const short8* Eh = (const short8*)ehi;
    const short8* El = (const short8*)elo;
    int bbase = blockIdx.x * 8 + w * 2;
    short8 pbh[2], pbl[2];
    #pragma unroll
    for (int ni = 0; ni < 2; ni++) {
        size_t o = ((size_t)(bbase + ni) * 8 + 0) * 64 + lane;
        pbh[ni] = Eh[o]; pbl[ni] = El[o];
    }
    __syncthreads();                                   // B1

    // ---- key GEMM (transposed, pipelined): acc[mi][ni][r] = key[s][b] ----
    // s = mi*32 + (r&3)+8*(r>>2)+4q ; b = b0 + w*64 + ni*32 + col
    f32x16 acc[2][2] = {};
    #pragma unroll
    for (int t = 0; t < 8; t++) {
        short8 cbh[2] = { pbh[0], pbh[1] };
        short8 cbl[2] = { pbl[0], pbl[1] };
        if (t < 7) {                                   // prefetch t+1
            #pragma unroll
            for (int ni = 0; ni < 2; ni++) {
                size_t o = ((size_t)(bbase + ni) * 8 + (t + 1)) * 64 + lane;
                pbh[ni] = Eh[o]; pbl[ni] = El[o];
            }
        }
        #pragma unroll
        for (int mi = 0; mi < 2; mi++) {
            short8 a_h = WsH[(mi * 8 + t) * 64 + lane];
            short8 a_l = WsL[(mi * 8 + t) * 64 + lane];
            #pragma unroll
            for (int ni = 0; ni < 2; ni++) {
                acc[mi][ni] = __builtin_amdgcn_mfma_f32_32x32x16_bf16(a_h, cbh[ni], acc[mi][ni], 0, 0, 0);
                acc[mi][ni] = __builtin_amdgcn_mfma_f32_32x32x16_bf16(a_h, cbl[ni], acc[mi][ni], 0, 0, 0);
                acc[mi][ni] = __builtin_amdgcn_mfma_f32_32x32x16_bf16(a_l, cbh[ni], acc[mi][ni], 0, 0, 0);
            }
        }
    }

    // ---- Gn quadrant (qi,qj) per wave from LDS fragments ----
    int qi = w & 1, qj = w >> 1;
    f32x16 gacc = {};
    #pragma unroll
    for (int t = 0; t < 8; t++) {
        short8 ah = WsH[(qi * 8 + t) * 64 + lane];
        short8 al = WsL[(qi * 8 + t) * 64 + lane];
        short8 bh = WsH[(qj * 8 + t) * 64 + lane];
        short8 bl = WsL[(qj * 8 + t) * 64 + lane];
        gacc = __builtin_amdgcn_mfma_f32_32x32x16_bf16(ah, bh, gacc, 0, 0, 0);
        gacc = __builtin_amdgcn_mfma_f32_32x32x16_bf16(ah, bl, gacc, 0, 0, 0);
        gacc = __builtin_amdgcn_mfma_f32_32x32x16_bf16(al, bh, gacc, 0, 0, 0);
    }
    __syncthreads();                                   // B2: Ws reads done
    #pragma unroll
    for (int r = 0; r < 16; r++) {
        int row = (r & 3) + 8 * (r >> 2) + 4 * q;
        Gs[(qi * 32 + row) * SS + qj * 32 + col] = gacc[r];   // gacc dies here
    }

    // ---- register-local top-8 per ni (u32 packed sort) ----
    uint32_t loc[2][8];
    #pragma unroll
    for (int ni = 0; ni < 2; ni++) {
        #pragma unroll
        for (int g = 0; g < 4; g++) {
            int mi = g >> 1, rb = (g & 1) * 8;
            uint32_t grp[8];
            #pragma unroll
            for (int j = 0; j < 8; j++) {
                int r = rb + j;
                int s = mi * 32 + (r & 3) + 8 * (r >> 2) + 4 * q;
                grp[j] = (fmono(acc[mi][ni][r]) & 0xFFFFFFC0u) | (uint32_t)(63 - s);
            }
            sort8_32(grp);
            if (g == 0) {
                #pragma unroll
                for (int j = 0; j < 8; j++) loc[ni][j] = grp[j];
            } else {
                merge8_32(loc[ni], grp);
            }
        }
    }
    // exchange: q=0 lane finalizes b(ni=0), q=1 finalizes b(ni=1); partner=lane^32
    uint32_t fin[8], rcv[8];
    #pragma unroll
    for (int i = 0; i < 8; i++) {
        uint32_t xc = q ? loc[0][i] : loc[1][i];
        rcv[i] = (uint32_t)__shfl_xor((int)xc, 32, 64);
        fin[i] = q ? loc[1][i] : loc[0][i];
    }
    // final top-8 SET (bitonic max of two sorted-desc 8-lists)
    uint32_t mx;
    {
        uint32_t t[8];
        #pragma unroll
        for (int i = 0; i < 8; i++)
            t[i] = fin[i] > rcv[7 - i] ? fin[i] : rcv[7 - i];
        mx = t[0] > t[7] ? t[0] : t[7];                  // overall max
        #pragma unroll
        for (int i = 0; i < 8; i++) fin[i] = t[i];
    }
    float kq[TOPKN]; int idx[TOPKN];
    #pragma unroll
    for (int k = 0; k < TOPKN; k++) {
        kq[k] = funmono(fin[k] & 0xFFFFFFC0u);
        idx[k] = 63 - (int)(fin[k] & 63u);
    }
    float mxkey = funmono(mx & 0xFFFFFFC0u);
    __syncthreads();                                   // B3: Gs ready

    // ---------------- epilogue: 1 lane per b ----------------
    int b = b0 + w * 64 + lane;
    float ne = nemb[b];
    float inv_ne = 1.0f / ne;

    float sc0 = (1.0f + mxkey * inv_ne) * 0.5f + EPSF;
    float wk[TOPKN], wsum = 0.f;
    #pragma unroll
    for (int k = 0; k < TOPKN; k++) {
        float sck = (1.0f + kq[k] * inv_ne) * 0.5f + EPSF;
        float ev = __expf(sck - sc0);
        wk[k] = ev; wsum += ev;
    }
    float winv = 1.0f / wsum;

    float vk[TOPKN];
    #pragma unroll
    for (int k = 0; k < TOPKN; k++) vk[k] = wk[k] * nwL[idx[k]];
    float dot2 = 0.f;
    #pragma unroll
    for (int k = 0; k < TOPKN; k++) dot2 += vk[k] * kq[k];
    float np2 = 0.f;
    #pragma unroll
    for (int j = 0; j < TOPKN; j++) {
        float vj = vk[j];
        np2 += vj * vj * Gs[idx[j] * (SS + 1)];
        #pragma unroll
        for (int k2 = j + 1; k2 < TOPKN; k2++)
            np2 += 2.0f * vj * vk[k2] * Gs[idx[j] * SS + idx[k2]];
    }
    dot2 *= winv;
    np2 *= winv * winv;

    float denom2 = fmaxf(sqrtf(fmaxf(np2, 0.f)) * ne, EPSF);
    float cos2 = dot2 / denom2;
    out[(size_t)b * CC + c] = ((1.0f + cos2) * 0.5f + EPSF) / 0.1f;
}

extern "C" void kernel_launch(void* const* d_in, const int* in_sizes, int n_in,
                              void* d_out, int out_size, void* d_ws, size_t ws_size,
                              hipStream_t stream) {
    const float* emb    = (const float*)d_in[0];
    const float* weight = (const float*)d_in[1];
    float* nw   = (float*)d_ws;                                   // 64 KB
    float* nemb = nw + CC * SS;                                   // 4 KB
    unsigned short* ehi = (unsigned short*)(nemb + BB);           // 256 KB
    unsigned short* elo = ehi + (size_t)BB * DD;                  // 256 KB
    unsigned short* whi = elo + (size_t)BB * DD;                  // 4 MB
    unsigned short* wlo = whi + (size_t)CC * SS * DD;             // 4 MB
    float* out = (float*)d_out;

    hipLaunchKernelGGL(split_kernel, dim3((BB + CC * SS) * 16 / 256), dim3(256), 0, stream,
                       emb, weight, ehi, elo, whi, wlo, nemb, nw);
    hipLaunchKernelGGL(main_kernel, dim3(BB / 256, CC), dim3(256), 0, stream,
                       ehi, elo, whi, wlo, nw, nemb, out);
}

// Round 15
// 85.828 us; speedup vs baseline: 1.0369x; 1.0369x over previous
//
#include <hip/hip_runtime.h>
#include <cstdint>
#include <cmath>

#define BB 1024
#define CC 256
#define SS 64
#define DD 128
#define TOPKN 8
#define EPSF 1e-8f

typedef __attribute__((ext_vector_type(8))) short short8;
typedef __attribute__((ext_vector_type(16))) float f32x16;

static __device__ __forceinline__ unsigned short f2bf(float x) {
    uint32_t u = __float_as_uint(x);
    uint32_t r = (u + 0x7FFFu + ((u >> 16) & 1u)) >> 16;   // RNE
    return (unsigned short)r;
}
static __device__ __forceinline__ float bf2f(unsigned short h) {
    return __uint_as_float(((uint32_t)h) << 16);
}

// u32 compare-exchange, descending. Packed key = (fmono(key)&~63)|(63-s):
// 2^-18-granular key + index tiebreak (lower s wins). Fits the 128-reg budget
// of 4 waves/SIMD (no spill; proven R13).
#define CEX32(a, b) { uint32_t _h = (a) > (b) ? (a) : (b); \
                      uint32_t _l = (a) > (b) ? (b) : (a); (a) = _h; (b) = _l; }

static __device__ __forceinline__ void sort8_32(uint32_t* v) {
    CEX32(v[0],v[1]); CEX32(v[2],v[3]); CEX32(v[4],v[5]); CEX32(v[6],v[7]);
    CEX32(v[0],v[2]); CEX32(v[1],v[3]); CEX32(v[4],v[6]); CEX32(v[5],v[7]);
    CEX32(v[1],v[2]); CEX32(v[5],v[6]);
    CEX32(v[0],v[4]); CEX32(v[1],v[5]); CEX32(v[2],v[6]); CEX32(v[3],v[7]);
    CEX32(v[2],v[4]); CEX32(v[3],v[5]);
    CEX32(v[1],v[2]); CEX32(v[3],v[4]); CEX32(v[5],v[6]);
}
// run := top-8 (sorted desc) of run ∪ cur; both sorted desc (bitonic merge).
static __device__ __forceinline__ void merge8_32(uint32_t* run, const uint32_t* cur) {
    uint32_t t[8];
    #pragma unroll
    for (int i = 0; i < 8; i++) t[i] = run[i] > cur[7-i] ? run[i] : cur[7-i];
    CEX32(t[0],t[4]); CEX32(t[1],t[5]); CEX32(t[2],t[6]); CEX32(t[3],t[7]);
    CEX32(t[0],t[2]); CEX32(t[1],t[3]); CEX32(t[4],t[6]); CEX32(t[5],t[7]);
    CEX32(t[0],t[1]); CEX32(t[2],t[3]); CEX32(t[4],t[5]); CEX32(t[6],t[7]);
    #pragma unroll
    for (int i = 0; i < 8; i++) run[i] = t[i];
}

// monotone map: float bits -> u32 preserving order
static __device__ __forceinline__ uint32_t fmono(float x) {
    uint32_t u = __float_as_uint(x);
    return u ^ (uint32_t)(((int32_t)u >> 31) | 0x80000000);
}
static __device__ __forceinline__ float funmono(uint32_t m) {
    uint32_t u = (m & 0x80000000u) ? (m ^ 0x80000000u) : ~m;
    return __uint_as_float(u);
}

// ---- kernel A: split emb (raw) and weight (row-normalized) into bf16 hi/lo
//      MFMA fragments + exact fp32 norms. (proven since R6) ----
__global__ __launch_bounds__(256) void split_kernel(const float* __restrict__ emb,
                                                    const float* __restrict__ weight,
                                                    unsigned short* __restrict__ ehi,
                                                    unsigned short* __restrict__ elo,
                                                    unsigned short* __restrict__ whi,
                                                    unsigned short* __restrict__ wlo,
                                                    float* __restrict__ nemb,
                                                    float* __restrict__ nw_g) {
    int gid = blockIdx.x * 256 + threadIdx.x;   // 16 threads per row
    int row = gid >> 4, kg = gid & 15;
    bool isEmb = row < BB;
    int r = isEmb ? row : row - BB;
    const float* src = isEmb ? emb : weight;
    const float4* sp = (const float4*)(src + (size_t)r * DD + kg * 8);
    float4 v0 = sp[0], v1 = sp[1];
    float x[8] = {v0.x, v0.y, v0.z, v0.w, v1.x, v1.y, v1.z, v1.w};
    float ss = 0.f;
    #pragma unroll
    for (int j = 0; j < 8; j++) ss += x[j] * x[j];
    #pragma unroll
    for (int off = 8; off; off >>= 1) ss += __shfl_xor(ss, off);

    float scale;
    if (isEmb) {
        if (kg == 0) nemb[r] = sqrtf(ss);
        scale = 1.0f;
    } else {
        if (kg == 0) nw_g[r] = sqrtf(ss);
        scale = 1.0f / sqrtf(fmaxf(ss, 1e-30f));
    }
    short8 h8, l8;
    #pragma unroll
    for (int j = 0; j < 8; j++) {
        float xs = x[j] * scale;
        unsigned short h = f2bf(xs);
        h8[j] = (short)h;
        l8[j] = (short)f2bf(xs - bf2f(h));
    }
    size_t o = ((size_t)(r >> 5) * 8 + (kg >> 1)) * 64 + (kg & 1) * 32 + (r & 31);
    if (isEmb) { ((short8*)ehi)[o] = h8; ((short8*)elo)[o] = l8; }
    else       { ((short8*)whi)[o] = h8; ((short8*)wlo)[o] = l8; }
}

// ---- kernel B (fused, transposed GEMM): D[s][b] = Wn[c] . emb^T.
//      R15: Gram MFMAs interleaved INTO the GEMM t-loop (independent MFMA work
//      covers e-frag load latency; no serial Gram tail). Grid (256,4): c on the
//      fast axis so the 4 same-c blocks share an XCD slot (W L2 locality).
//      (256,4): ~116 live regs < 128 -> no spill; 4 blocks/CU, zero tail. ----
__global__ __launch_bounds__(256, 4) void main_kernel(const unsigned short* __restrict__ ehi,
                                                      const unsigned short* __restrict__ elo,
                                                      const unsigned short* __restrict__ whi,
                                                      const unsigned short* __restrict__ wlo,
                                                      const float* __restrict__ nw_g,
                                                      const float* __restrict__ nemb,
                                                      float* __restrict__ out) {
    __shared__ __align__(16) float uni[8192];   // 32 KB: Ws, later Gs (16 KB)
    __shared__ float nwL[SS];
    short8* WsH = (short8*)uni;                 // [tile(2)][t(8)][lane(64)]
    short8* WsL = WsH + 1024;
    float* Gs = uni;                            // life 2: Gn 64x64

    int tid = threadIdx.x, lane = tid & 63, w = tid >> 6;
    int q = lane >> 5, col = lane & 31;
    int c = blockIdx.x, b0 = blockIdx.y * 256;  // c fast-varying -> XCD locality

    // ---- life 1: stage W[c] fragments + nw[c] ----
    const short8* whg = (const short8*)whi + (size_t)c * 1024;
    const short8* wlg = (const short8*)wlo + (size_t)c * 1024;
    #pragma unroll
    for (int j = 0; j < 4; j++) {
        WsH[j * 256 + tid] = whg[j * 256 + tid];
        WsL[j * 256 + tid] = wlg[j * 256 + tid];
    }
    if (tid < SS) nwL[tid] = nw_g[c * SS + tid];
    __syncthreads();                                   // B1

    // ---- merged t-loop: 12 GEMM MFMAs + 3 Gram MFMAs per t ----
    // GEMM: s = mi*32 + (r&3)+8*(r>>2)+4q ; b = b0 + w*64 + ni*32 + col
    // Gram: wave quadrant (qi,qj) of Gn = Wn Wn^T
    const short8* Eh = (const short8*)ehi;
    const short8* El = (const short8*)elo;
    int bbase = blockIdx.y * 8 + w * 2;
    int qi = w & 1, qj = w >> 1;
    f32x16 acc[2][2] = {};
    f32x16 gacc = {};
    #pragma unroll 2
    for (int t = 0; t < 8; t++) {
        short8 b_h[2], b_l[2];
        #pragma unroll
        for (int ni = 0; ni < 2; ni++) {
            size_t o = ((size_t)(bbase + ni) * 8 + t) * 64 + lane;
            b_h[ni] = Eh[o]; b_l[ni] = El[o];
        }
        // Gram first: operands are LDS-resident -> MFMA pipe busy while e-frags fly
        {
            short8 gah = WsH[(qi * 8 + t) * 64 + lane];
            short8 gal = WsL[(qi * 8 + t) * 64 + lane];
            short8 gbh = WsH[(qj * 8 + t) * 64 + lane];
            short8 gbl = WsL[(qj * 8 + t) * 64 + lane];
            gacc = __builtin_amdgcn_mfma_f32_32x32x16_bf16(gah, gbh, gacc, 0, 0, 0);
            gacc = __builtin_amdgcn_mfma_f32_32x32x16_bf16(gah, gbl, gacc, 0, 0, 0);
            gacc = __builtin_amdgcn_mfma_f32_32x32x16_bf16(gal, gbh, gacc, 0, 0, 0);
        }
        #pragma unroll
        for (int mi = 0; mi < 2; mi++) {
            short8 a_h = WsH[(mi * 8 + t) * 64 + lane];
            short8 a_l = WsL[(mi * 8 + t) * 64 + lane];
            #pragma unroll
            for (int ni = 0; ni < 2; ni++) {
                acc[mi][ni] = __builtin_amdgcn_mfma_f32_32x32x16_bf16(a_h, b_h[ni], acc[mi][ni], 0, 0, 0);
                acc[mi][ni] = __builtin_amdgcn_mfma_f32_32x32x16_bf16(a_h, b_l[ni], acc[mi][ni], 0, 0, 0);
                acc[mi][ni] = __builtin_amdgcn_mfma_f32_32x32x16_bf16(a_l, b_h[ni], acc[mi][ni], 0, 0, 0);
            }
        }
    }
    __syncthreads();                                   // B2: Ws reads done
    #pragma unroll
    for (int r = 0; r < 16; r++) {
        int row = (r & 3) + 8 * (r >> 2) + 4 * q;
        Gs[(qi * 32 + row) * SS + qj * 32 + col] = gacc[r];   // gacc dies here
    }

    // ---- register-local top-8 per ni (u32 packed sort) ----
    uint32_t loc[2][8];
    #pragma unroll
    for (int ni = 0; ni < 2; ni++) {
        #pragma unroll
        for (int g = 0; g < 4; g++) {
            int mi = g >> 1, rb = (g & 1) * 8;
            uint32_t grp[8];
            #pragma unroll
            for (int j = 0; j < 8; j++) {
                int r = rb + j;
                int s = mi * 32 + (r & 3) + 8 * (r >> 2) + 4 * q;
                grp[j] = (fmono(acc[mi][ni][r]) & 0xFFFFFFC0u) | (uint32_t)(63 - s);
            }
            sort8_32(grp);
            if (g == 0) {
                #pragma unroll
                for (int j = 0; j < 8; j++) loc[ni][j] = grp[j];
            } else {
                merge8_32(loc[ni], grp);
            }
        }
    }
    // exchange: q=0 lane finalizes b(ni=0), q=1 finalizes b(ni=1); partner=lane^32
    uint32_t fin[8], rcv[8];
    #pragma unroll
    for (int i = 0; i < 8; i++) {
        uint32_t xc = q ? loc[0][i] : loc[1][i];
        rcv[i] = (uint32_t)__shfl_xor((int)xc, 32, 64);
        fin[i] = q ? loc[1][i] : loc[0][i];
    }
    // final top-8 SET (bitonic max of two sorted-desc 8-lists)
    uint32_t mx;
    {
        uint32_t t[8];
        #pragma unroll
        for (int i = 0; i < 8; i++)
            t[i] = fin[i] > rcv[7 - i] ? fin[i] : rcv[7 - i];
        mx = t[0] > t[7] ? t[0] : t[7];                  // overall max
        #pragma unroll
        for (int i = 0; i < 8; i++) fin[i] = t[i];
    }
    float kq[TOPKN]; int idx[TOPKN];
    #pragma unroll
    for (int k = 0; k < TOPKN; k++) {
        kq[k] = funmono(fin[k] & 0xFFFFFFC0u);
        idx[k] = 63 - (int)(fin[k] & 63u);
    }
    float mxkey = funmono(mx & 0xFFFFFFC0u);
    __syncthreads();                                   // B3: Gs ready

    // ---------------- epilogue: 1 lane per b ----------------
    int b = b0 + w * 64 + lane;
    float ne = nemb[b];
    float inv_ne = 1.0f / ne;

    float sc0 = (1.0f + mxkey * inv_ne) * 0.5f + EPSF;
    float wk[TOPKN], wsum = 0.f;
    #pragma unroll
    for (int k = 0; k < TOPKN; k++) {
        float sck = (1.0f + kq[k] * inv_ne) * 0.5f + EPSF;
        float ev = __expf(sck - sc0);
        wk[k] = ev; wsum += ev;
    }
    float winv = 1.0f / wsum;

    float vk[TOPKN];
    #pragma unroll
    for (int k = 0; k < TOPKN; k++) vk[k] = wk[k] * nwL[idx[k]];
    float dot2 = 0.f;
    #pragma unroll
    for (int k = 0; k < TOPKN; k++) dot2 += vk[k] * kq[k];
    float np2 = 0.f;
    #pragma unroll
    for (int j = 0; j < TOPKN; j++) {
        float vj = vk[j];
        np2 += vj * vj * Gs[idx[j] * (SS + 1)];
        #pragma unroll
        for (int k2 = j + 1; k2 < TOPKN; k2++)
            np2 += 2.0f * vj * vk[k2] * Gs[idx[j] * SS + idx[k2]];
    }
    dot2 *= winv;
    np2 *= winv * winv;

    float denom2 = fmaxf(sqrtf(fmaxf(np2, 0.f)) * ne, EPSF);
    float cos2 = dot2 / denom2;
    out[(size_t)b * CC + c] = ((1.0f + cos2) * 0.5f + EPSF) / 0.1f;
}

extern "C" void kernel_launch(void* const* d_in, const int* in_sizes, int n_in,
                              void* d_out, int out_size, void* d_ws, size_t ws_size,
                              hipStream_t stream) {
    const float* emb    = (const float*)d_in[0];
    const float* weight = (const float*)d_in[1];
    float* nw   = (float*)d_ws;                                   // 64 KB
    float* nemb = nw + CC * SS;                                   // 4 KB
    unsigned short* ehi = (unsigned short*)(nemb + BB);           // 256 KB
    unsigned short* elo = ehi + (size_t)BB * DD;                  // 256 KB
    unsigned short* whi = elo + (size_t)BB * DD;                  // 4 MB
    unsigned short* wlo = whi + (size_t)CC * SS * DD;             // 4 MB
    float* out = (float*)d_out;

    hipLaunchKernelGGL(split_kernel, dim3((BB + CC * SS) * 16 / 256), dim3(256), 0, stream,
                       emb, weight, ehi, elo, whi, wlo, nemb, nw);
    hipLaunchKernelGGL(main_kernel, dim3(CC, BB / 256), dim3(256), 0, stream,
                       ehi, elo, whi, wlo, nw, nemb, out);
}

// Round 16
// 84.816 us; speedup vs baseline: 1.0493x; 1.0119x over previous
//
#include <hip/hip_runtime.h>
#include <cstdint>
#include <cmath>

#define BB 1024
#define CC 256
#define SS 64
#define DD 128
#define TOPKN 8
#define EPSF 1e-8f

typedef __attribute__((ext_vector_type(8))) short short8;
typedef __attribute__((ext_vector_type(16))) float f32x16;

static __device__ __forceinline__ unsigned short f2bf(float x) {
    uint32_t u = __float_as_uint(x);
    uint32_t r = (u + 0x7FFFu + ((u >> 16) & 1u)) >> 16;   // RNE
    return (unsigned short)r;
}
static __device__ __forceinline__ float bf2f(unsigned short h) {
    return __uint_as_float(((uint32_t)h) << 16);
}

// u32 compare-exchange, descending. Packed key = (fmono(key)&~63)|(63-s):
// 2^-18-granular key + index tiebreak (lower s wins). Fits the 128-reg budget
// of 4 waves/SIMD (no spill; proven R13).
#define CEX32(a, b) { uint32_t _h = (a) > (b) ? (a) : (b); \
                      uint32_t _l = (a) > (b) ? (b) : (a); (a) = _h; (b) = _l; }

static __device__ __forceinline__ void sort8_32(uint32_t* v) {
    CEX32(v[0],v[1]); CEX32(v[2],v[3]); CEX32(v[4],v[5]); CEX32(v[6],v[7]);
    CEX32(v[0],v[2]); CEX32(v[1],v[3]); CEX32(v[4],v[6]); CEX32(v[5],v[7]);
    CEX32(v[1],v[2]); CEX32(v[5],v[6]);
    CEX32(v[0],v[4]); CEX32(v[1],v[5]); CEX32(v[2],v[6]); CEX32(v[3],v[7]);
    CEX32(v[2],v[4]); CEX32(v[3],v[5]);
    CEX32(v[1],v[2]); CEX32(v[3],v[4]); CEX32(v[5],v[6]);
}
// run := top-8 (sorted desc) of run ∪ cur; both sorted desc (bitonic merge).
static __device__ __forceinline__ void merge8_32(uint32_t* run, const uint32_t* cur) {
    uint32_t t[8];
    #pragma unroll
    for (int i = 0; i < 8; i++) t[i] = run[i] > cur[7-i] ? run[i] : cur[7-i];
    CEX32(t[0],t[4]); CEX32(t[1],t[5]); CEX32(t[2],t[6]); CEX32(t[3],t[7]);
    CEX32(t[0],t[2]); CEX32(t[1],t[3]); CEX32(t[4],t[6]); CEX32(t[5],t[7]);
    CEX32(t[0],t[1]); CEX32(t[2],t[3]); CEX32(t[4],t[5]); CEX32(t[6],t[7]);
    #pragma unroll
    for (int i = 0; i < 8; i++) run[i] = t[i];
}

// monotone map: float bits -> u32 preserving order
static __device__ __forceinline__ uint32_t fmono(float x) {
    uint32_t u = __float_as_uint(x);
    return u ^ (uint32_t)(((int32_t)u >> 31) | 0x80000000);
}
static __device__ __forceinline__ float funmono(uint32_t m) {
    uint32_t u = (m & 0x80000000u) ? (m ^ 0x80000000u) : ~m;
    return __uint_as_float(u);
}

// ---- kernel A: split emb ONLY into bf16 hi/lo MFMA fragments + ||emb||.
//      (W split now lives inside main_kernel's staging phase.) ----
__global__ __launch_bounds__(256) void split_kernel(const float* __restrict__ emb,
                                                    unsigned short* __restrict__ ehi,
                                                    unsigned short* __restrict__ elo,
                                                    float* __restrict__ nemb) {
    int gid = blockIdx.x * 256 + threadIdx.x;   // 16 threads per row
    int r = gid >> 4, kg = gid & 15;
    const float4* sp = (const float4*)(emb + (size_t)r * DD + kg * 8);
    float4 v0 = sp[0], v1 = sp[1];
    float x[8] = {v0.x, v0.y, v0.z, v0.w, v1.x, v1.y, v1.z, v1.w};
    float ss = 0.f;
    #pragma unroll
    for (int j = 0; j < 8; j++) ss += x[j] * x[j];
    #pragma unroll
    for (int off = 8; off; off >>= 1) ss += __shfl_xor(ss, off);
    if (kg == 0) nemb[r] = sqrtf(ss);

    short8 h8, l8;
    #pragma unroll
    for (int j = 0; j < 8; j++) {
        unsigned short h = f2bf(x[j]);
        h8[j] = (short)h;
        l8[j] = (short)f2bf(x[j] - bf2f(h));
    }
    size_t o = ((size_t)(r >> 5) * 8 + (kg >> 1)) * 64 + (kg & 1) * 32 + (r & 31);
    ((short8*)ehi)[o] = h8;
    ((short8*)elo)[o] = l8;
}

// ---- kernel B (fused): in-block W split -> LDS frags, transposed GEMM with
//      interleaved Gram MFMAs, register-local u32 top-8, bilinear epilogue.
//      (256,4): ~116 live regs < 128 -> no spill; 4 blocks/CU, zero tail. ----
__global__ __launch_bounds__(256, 4) void main_kernel(const unsigned short* __restrict__ ehi,
                                                      const unsigned short* __restrict__ elo,
                                                      const float* __restrict__ weight,
                                                      const float* __restrict__ nemb,
                                                      float* __restrict__ out) {
    __shared__ __align__(16) float uni[8192];   // 32 KB: Ws frags, later Gs (16 KB)
    __shared__ float nwL[SS];
    short8* WsH = (short8*)uni;                 // [tile(2)][t(8)][lane(64)]
    short8* WsL = WsH + 1024;
    float* Gs = uni;                            // life 2: Gn 64x64

    int tid = threadIdx.x, lane = tid & 63, w = tid >> 6;
    int q = lane >> 5, col = lane & 31;
    int c = blockIdx.x, b0 = blockIdx.y * 256;  // c fast-varying -> XCD locality

    // ---- life 1: W[c] fp32 -> norms + bf16 hi/lo frags, straight into LDS ----
    // thread <-> short8-group G = tid + 256j: row r = (tid>>4)+16j, kg = tid&15.
    // Coalesced: consecutive lanes read 32B-strided float4 pairs.
    {
        const float4* wsrc = (const float4*)(weight + (size_t)c * SS * DD);
        float x[4][8];
        float ss4[4];
        #pragma unroll
        for (int j = 0; j < 4; j++) {
            const float4* p = wsrc + (size_t)(tid + 256 * j) * 2;
            float4 a = p[0], b4 = p[1];
            x[j][0] = a.x;  x[j][1] = a.y;  x[j][2] = a.z;  x[j][3] = a.w;
            x[j][4] = b4.x; x[j][5] = b4.y; x[j][6] = b4.z; x[j][7] = b4.w;
            float s = 0.f;
            #pragma unroll
            for (int i = 0; i < 8; i++) s += x[j][i] * x[j][i];
            ss4[j] = s;
        }
        // reduce over the 16 lanes sharing each row (lanes differ in kg=tid&15)
        #pragma unroll
        for (int off = 1; off < 16; off <<= 1)
            #pragma unroll
            for (int j = 0; j < 4; j++) ss4[j] += __shfl_xor(ss4[j], off, 64);

        int kg = tid & 15;
        #pragma unroll
        for (int j = 0; j < 4; j++) {
            int r = (tid >> 4) + 16 * j;
            if (kg == 0) nwL[r] = sqrtf(ss4[j]);
            float scale = 1.0f / sqrtf(fmaxf(ss4[j], 1e-30f));
            short8 h8, l8;
            #pragma unroll
            for (int i = 0; i < 8; i++) {
                float xs = x[j][i] * scale;
                unsigned short h = f2bf(xs);
                h8[i] = (short)h;
                l8[i] = (short)f2bf(xs - bf2f(h));
            }
            int o = ((r >> 5) * 8 + (kg >> 1)) * 64 + (kg & 1) * 32 + (r & 31);
            WsH[o] = h8;
            WsL[o] = l8;
        }
    }
    __syncthreads();                                   // B1

    // ---- merged t-loop: 12 GEMM MFMAs + 3 Gram MFMAs per t ----
    // GEMM: s = mi*32 + (r&3)+8*(r>>2)+4q ; b = b0 + w*64 + ni*32 + col
    const short8* Eh = (const short8*)ehi;
    const short8* El = (const short8*)elo;
    int bbase = blockIdx.y * 8 + w * 2;
    int qi = w & 1, qj = w >> 1;
    f32x16 acc[2][2] = {};
    f32x16 gacc = {};
    #pragma unroll 2
    for (int t = 0; t < 8; t++) {
        short8 b_h[2], b_l[2];
        #pragma unroll
        for (int ni = 0; ni < 2; ni++) {
            size_t o = ((size_t)(bbase + ni) * 8 + t) * 64 + lane;
            b_h[ni] = Eh[o]; b_l[ni] = El[o];
        }
        // Gram first: LDS-resident operands keep the MFMA pipe busy during loads
        {
            short8 gah = WsH[(qi * 8 + t) * 64 + lane];
            short8 gal = WsL[(qi * 8 + t) * 64 + lane];
            short8 gbh = WsH[(qj * 8 + t) * 64 + lane];
            short8 gbl = WsL[(qj * 8 + t) * 64 + lane];
            gacc = __builtin_amdgcn_mfma_f32_32x32x16_bf16(gah, gbh, gacc, 0, 0, 0);
            gacc = __builtin_amdgcn_mfma_f32_32x32x16_bf16(gah, gbl, gacc, 0, 0, 0);
            gacc = __builtin_amdgcn_mfma_f32_32x32x16_bf16(gal, gbh, gacc, 0, 0, 0);
        }
        #pragma unroll
        for (int mi = 0; mi < 2; mi++) {
            short8 a_h = WsH[(mi * 8 + t) * 64 + lane];
            short8 a_l = WsL[(mi * 8 + t) * 64 + lane];
            #pragma unroll
            for (int ni = 0; ni < 2; ni++) {
                acc[mi][ni] = __builtin_amdgcn_mfma_f32_32x32x16_bf16(a_h, b_h[ni], acc[mi][ni], 0, 0, 0);
                acc[mi][ni] = __builtin_amdgcn_mfma_f32_32x32x16_bf16(a_h, b_l[ni], acc[mi][ni], 0, 0, 0);
                acc[mi][ni] = __builtin_amdgcn_mfma_f32_32x32x16_bf16(a_l, b_h[ni], acc[mi][ni], 0, 0, 0);
            }
        }
    }
    __syncthreads();                                   // B2: Ws reads done
    #pragma unroll
    for (int r = 0; r < 16; r++) {
        int row = (r & 3) + 8 * (r >> 2) + 4 * q;
        Gs[(qi * 32 + row) * SS + qj * 32 + col] = gacc[r];   // gacc dies here
    }

    // ---- register-local top-8 per ni (u32 packed sort) ----
    uint32_t loc[2][8];
    #pragma unroll
    for (int ni = 0; ni < 2; ni++) {
        #pragma unroll
        for (int g = 0; g < 4; g++) {
            int mi = g >> 1, rb = (g & 1) * 8;
            uint32_t grp[8];
            #pragma unroll
            for (int j = 0; j < 8; j++) {
                int r = rb + j;
                int s = mi * 32 + (r & 3) + 8 * (r >> 2) + 4 * q;
                grp[j] = (fmono(acc[mi][ni][r]) & 0xFFFFFFC0u) | (uint32_t)(63 - s);
            }
            sort8_32(grp);
            if (g == 0) {
                #pragma unroll
                for (int j = 0; j < 8; j++) loc[ni][j] = grp[j];
            } else {
                merge8_32(loc[ni], grp);
            }
        }
    }
    // exchange: q=0 lane finalizes b(ni=0), q=1 finalizes b(ni=1); partner=lane^32
    uint32_t fin[8], rcv[8];
    #pragma unroll
    for (int i = 0; i < 8; i++) {
        uint32_t xc = q ? loc[0][i] : loc[1][i];
        rcv[i] = (uint32_t)__shfl_xor((int)xc, 32, 64);
        fin[i] = q ? loc[1][i] : loc[0][i];
    }
    // final top-8 SET (bitonic max of two sorted-desc 8-lists)
    uint32_t mx;
    {
        uint32_t t[8];
        #pragma unroll
        for (int i = 0; i < 8; i++)
            t[i] = fin[i] > rcv[7 - i] ? fin[i] : rcv[7 - i];
        mx = t[0] > t[7] ? t[0] : t[7];                  // overall max
        #pragma unroll
        for (int i = 0; i < 8; i++) fin[i] = t[i];
    }
    float kq[TOPKN]; int idx[TOPKN];
    #pragma unroll
    for (int k = 0; k < TOPKN; k++) {
        kq[k] = funmono(fin[k] & 0xFFFFFFC0u);
        idx[k] = 63 - (int)(fin[k] & 63u);
    }
    float mxkey = funmono(mx & 0xFFFFFFC0u);
    __syncthreads();                                   // B3: Gs ready

    // ---------------- epilogue: 1 lane per b ----------------
    int b = b0 + w * 64 + lane;
    float ne = nemb[b];
    float inv_ne = 1.0f / ne;

    float sc0 = (1.0f + mxkey * inv_ne) * 0.5f + EPSF;
    float wk[TOPKN], wsum = 0.f;
    #pragma unroll
    for (int k = 0; k < TOPKN; k++) {
        float sck = (1.0f + kq[k] * inv_ne) * 0.5f + EPSF;
        float ev = __expf(sck - sc0);
        wk[k] = ev; wsum += ev;
    }
    float winv = 1.0f / wsum;

    float vk[TOPKN];
    #pragma unroll
    for (int k = 0; k < TOPKN; k++) vk[k] = wk[k] * nwL[idx[k]];
    float dot2 = 0.f;
    #pragma unroll
    for (int k = 0; k < TOPKN; k++) dot2 += vk[k] * kq[k];
    float np2 = 0.f;
    #pragma unroll
    for (int j = 0; j < TOPKN; j++) {
        float vj = vk[j];
        np2 += vj * vj * Gs[idx[j] * (SS + 1)];
        #pragma unroll
        for (int k2 = j + 1; k2 < TOPKN; k2++)
            np2 += 2.0f * vj * vk[k2] * Gs[idx[j] * SS + idx[k2]];
    }
    dot2 *= winv;
    np2 *= winv * winv;

    float denom2 = fmaxf(sqrtf(fmaxf(np2, 0.f)) * ne, EPSF);
    float cos2 = dot2 / denom2;
    out[(size_t)b * CC + c] = ((1.0f + cos2) * 0.5f + EPSF) / 0.1f;
}

extern "C" void kernel_launch(void* const* d_in, const int* in_sizes, int n_in,
                              void* d_out, int out_size, void* d_ws, size_t ws_size,
                              hipStream_t stream) {
    const float* emb    = (const float*)d_in[0];
    const float* weight = (const float*)d_in[1];
    float* nemb = (float*)d_ws;                                   // 4 KB
    unsigned short* ehi = (unsigned short*)(nemb + BB);           // 256 KB
    unsigned short* elo = ehi + (size_t)BB * DD;                  // 256 KB
    float* out = (float*)d_out;

    hipLaunchKernelGGL(split_kernel, dim3(BB * 16 / 256), dim3(256), 0, stream,
                       emb, ehi, elo, nemb);
    hipLaunchKernelGGL(main_kernel, dim3(CC, BB / 256), dim3(256), 0, stream,
                       ehi, elo, weight, nemb, out);
}